// Round 1
// baseline (1046.474 us; speedup 1.0000x reference)
//
#include <hip/hip_runtime.h>

#define DD 8
#define SS 64
#define HH 128
#define OUTD 8
#define TT 2049
#define BB 32
#define WINW 16
#define NWIN 128
#define PP 28

__device__ __forceinline__ float softplus_f(float x){
    return fmaxf(x, 0.f) + log1pf(__expf(-fabsf(x)));
}
__device__ __forceinline__ float sigmoid_f(float x){
    return 1.f / (1.f + __expf(-x));
}
__device__ __forceinline__ float tanh_f(float x){
    float e = __expf(2.f * x);
    return 1.f - 2.f / (e + 1.f);
}

// ---------------- signatures: s1 (B,NWIN,D), s2 (B,NWIN,P) ----------------
__global__ void sig_kernel(const float* __restrict__ x,
                           float* __restrict__ s1o, float* __restrict__ s2o){
    int w = blockIdx.x * blockDim.x + threadIdx.x;
    if (w >= BB * NWIN) return;
    int b = w >> 7, n = w & (NWIN - 1);
    const float* xp = x + ((size_t)b * TT + (size_t)n * WINW) * DD;
    float prev[DD], cum[DD], s1v[DD], M[DD][DD];
    #pragma unroll
    for (int i = 0; i < DD; ++i){
        cum[i] = 0.f; s1v[i] = 0.f;
        #pragma unroll
        for (int j = 0; j < DD; ++j) M[i][j] = 0.f;
    }
    #pragma unroll
    for (int i = 0; i < DD; ++i) prev[i] = xp[i];
    for (int t = 0; t < WINW; ++t){
        float cur[DD], del[DD];
        #pragma unroll
        for (int i = 0; i < DD; ++i) cur[i] = xp[(t + 1) * DD + i];
        #pragma unroll
        for (int i = 0; i < DD; ++i) del[i] = cur[i] - prev[i];
        #pragma unroll
        for (int i = 0; i < DD; ++i){
            #pragma unroll
            for (int j = 0; j < DD; ++j) M[i][j] += cum[i] * del[j];
        }
        #pragma unroll
        for (int i = 0; i < DD; ++i){ cum[i] += del[i]; s1v[i] += del[i]; prev[i] = cur[i]; }
    }
    #pragma unroll
    for (int i = 0; i < DD; ++i) s1o[(size_t)w * DD + i] = s1v[i];
    int p = 0;
    #pragma unroll
    for (int i = 0; i < DD; ++i){
        #pragma unroll
        for (int j = i + 1; j < DD; ++j){ s2o[(size_t)w * PP + p] = 0.5f * (M[i][j] - M[j][i]); ++p; }
    }
}

// ---------------- main scan: one block per batch element ----------------
__global__ __launch_bounds__(512, 2) void scan_kernel(
    const float* __restrict__ x,
    const float* __restrict__ Wi0, const float* __restrict__ bi0,
    const float* __restrict__ Wi1, const float* __restrict__ bi1,
    const float* __restrict__ Wi2, const float* __restrict__ bi2,
    const float* __restrict__ Wv0, const float* __restrict__ bv0,
    const float* __restrict__ Wv1, const float* __restrict__ bv1,
    const float* __restrict__ Wv2, const float* __restrict__ bv2,
    const float* __restrict__ Wr,  const float* __restrict__ br,
    const float* __restrict__ s1g, const float* __restrict__ s2g,
    float* __restrict__ out)
{
    const int tid = threadIdx.x;
    const int b   = blockIdx.x;
    const int r   = tid & 127;   // row for W0/W1 stages
    const int q   = tid >> 7;    // K-quarter for W0/W1 stages
    const int dj  = tid >> 6;    // d of W2 row tid

    __shared__ __align__(16) float z0f[HH], s0p[HH], z1f[HH], s1pL[HH];
    __shared__ __align__(16) float hf[SS];
    __shared__ __align__(16) float Vl[DD * SS];
    __shared__ __align__(16) float uf[DD * SS];
    __shared__ __align__(16) float t0f[DD][HH];
    __shared__ __align__(16) float qf[DD][HH];
    __shared__ __align__(16) float part4[HH][5];      // padded
    __shared__ __align__(16) float part8[HH][DD][5];  // padded
    __shared__ __align__(16) float Rv[512];
    __shared__ float aL[DD];
    __shared__ float bcoL[PP];
    __shared__ __align__(16) float bv0L[HH], bv1L[HH], bv2L[512];
    __shared__ __align__(16) float WrL[OUTD * SS];
    __shared__ float brL[OUTD];

    // -------- persistent register-resident weights --------
    float w2row[128];   // Wv2[tid, :]
    float w1r[32];      // Wv1[r, q*32 .. q*32+31]
    float w0r[16];      // Wv0[r, q*16 .. q*16+15]
    {
        const float4* s2_ = (const float4*)(Wv2 + (size_t)tid * HH);
        #pragma unroll
        for (int k = 0; k < 32; ++k){
            float4 v = s2_[k];
            w2row[4*k] = v.x; w2row[4*k+1] = v.y; w2row[4*k+2] = v.z; w2row[4*k+3] = v.w;
        }
        const float4* s1_ = (const float4*)(Wv1 + (size_t)r * HH + q * 32);
        #pragma unroll
        for (int k = 0; k < 8; ++k){
            float4 v = s1_[k];
            w1r[4*k] = v.x; w1r[4*k+1] = v.y; w1r[4*k+2] = v.z; w1r[4*k+3] = v.w;
        }
        const float4* s0_ = (const float4*)(Wv0 + (size_t)r * SS + q * 16);
        #pragma unroll
        for (int k = 0; k < 4; ++k){
            float4 v = s0_[k];
            w0r[4*k] = v.x; w0r[4*k+1] = v.y; w0r[4*k+2] = v.z; w0r[4*k+3] = v.w;
        }
    }
    if (tid < HH){ bv0L[tid] = bv0[tid]; bv1L[tid] = bv1[tid]; }
    bv2L[tid] = bv2[tid];
    WrL[tid]  = Wr[tid];           // 512 = OUTD*SS
    if (tid < OUTD) brL[tid] = br[tid];
    __syncthreads();

    const float4* hfv = (const float4*)hf;
    const float4* z0v = (const float4*)z0f;
    const float4* z1v = (const float4*)z1f;
    const float4* ufv = (const float4*)uf;

    // -------- initial MLP: h0 = Wi2 @ sp(Wi1 @ sp(Wi0 @ x0 + bi0) + bi1) + bi2 --------
    if (tid < HH){
        float acc = bi0[tid];
        const float* x0 = x + (size_t)b * TT * DD;
        #pragma unroll
        for (int c = 0; c < DD; ++c) acc += Wi0[tid * DD + c] * x0[c];
        z0f[tid] = softplus_f(acc);
    }
    __syncthreads();
    if (tid < HH){
        float acc = bi1[tid];
        #pragma unroll 4
        for (int c = 0; c < HH; ++c) acc += Wi1[(size_t)tid * HH + c] * z0f[c];
        z1f[tid] = softplus_f(acc);
    }
    __syncthreads();
    if (tid < SS){
        float acc = bi2[tid];
        #pragma unroll 4
        for (int c = 0; c < HH; ++c) acc += Wi2[(size_t)tid * HH + c] * z1f[c];
        hf[tid] = acc;
    }
    __syncthreads();
    if (tid < OUTD){
        float acc = brL[tid];
        #pragma unroll
        for (int c = 0; c < SS; ++c) acc += WrL[tid * SS + c] * hf[c];
        out[(size_t)b * (NWIN + 1) * OUTD + tid] = acc;
    }

    // -------- scan over NWIN windows --------
    for (int n = 0; n < NWIN; ++n){
        if (tid < DD) aL[tid]   = s1g[((size_t)b * NWIN + n) * DD + tid];
        if (tid < PP) bcoL[tid] = s2g[((size_t)b * NWIN + n) * PP + tid];

        // S1: p0 partials (W0 @ h)
        {
            float acc = 0.f;
            #pragma unroll
            for (int k4 = 0; k4 < 4; ++k4){
                float4 hx = hfv[q * 4 + k4];
                acc += w0r[4*k4+0]*hx.x + w0r[4*k4+1]*hx.y + w0r[4*k4+2]*hx.z + w0r[4*k4+3]*hx.w;
            }
            part4[r][q] = acc;
        }
        __syncthreads();
        if (tid < HH){
            float p0 = part4[tid][0] + part4[tid][1] + part4[tid][2] + part4[tid][3] + bv0L[tid];
            z0f[tid] = softplus_f(p0);
            s0p[tid] = sigmoid_f(p0);
        }
        __syncthreads();

        // S3: p1 partials (W1 @ z0)
        {
            float acc = 0.f;
            #pragma unroll
            for (int k4 = 0; k4 < 8; ++k4){
                float4 zx = z0v[q * 8 + k4];
                acc += w1r[4*k4+0]*zx.x + w1r[4*k4+1]*zx.y + w1r[4*k4+2]*zx.z + w1r[4*k4+3]*zx.w;
            }
            part4[r][q] = acc;
        }
        __syncthreads();
        if (tid < HH){
            float p1 = part4[tid][0] + part4[tid][1] + part4[tid][2] + part4[tid][3] + bv1L[tid];
            z1f[tid]  = softplus_f(p1);
            s1pL[tid] = sigmoid_f(p1);
        }
        __syncthreads();

        // S4: V row tid = tanh(Wv2[tid,:] @ z1 + bv2)
        float Vj, tpj;
        {
            float acc = bv2L[tid];
            #pragma unroll
            for (int k4 = 0; k4 < 32; ++k4){
                float4 zx = z1v[k4];
                acc += w2row[4*k4+0]*zx.x + w2row[4*k4+1]*zx.y + w2row[4*k4+2]*zx.z + w2row[4*k4+3]*zx.w;
            }
            Vj  = tanh_f(acc);
            tpj = 1.f - Vj * Vj;
            Vl[tid] = Vj;
        }
        __syncthreads();

        // u[d][c] = sum_e C[d][e] * V[e][c], C from Lyndon coeffs
        {
            int d = dj, c = tid & 63;
            float acc = 0.f;
            #pragma unroll
            for (int e = 0; e < DD; ++e){
                float coef;
                if (e == d)      coef = 0.f;
                else if (e < d)  coef =  bcoL[((e * (15 - e)) >> 1) + d - e - 1];
                else             coef = -bcoL[((d * (15 - d)) >> 1) + e - d - 1];
                acc += coef * Vl[e * SS + c];
            }
            uf[tid] = acc;
        }
        __syncthreads();

        // S7: t0 partials (W0 @ u[d]), 8 tangents
        {
            float acc7[DD];
            #pragma unroll
            for (int d = 0; d < DD; ++d) acc7[d] = 0.f;
            #pragma unroll
            for (int d = 0; d < DD; ++d){
                #pragma unroll
                for (int k4 = 0; k4 < 4; ++k4){
                    float4 ux = ufv[d * 16 + q * 4 + k4];
                    acc7[d] += w0r[4*k4+0]*ux.x + w0r[4*k4+1]*ux.y + w0r[4*k4+2]*ux.z + w0r[4*k4+3]*ux.w;
                }
            }
            #pragma unroll
            for (int d = 0; d < DD; ++d) part8[r][d][q] = acc7[d];
        }
        __syncthreads();
        #pragma unroll
        for (int rep = 0; rep < 2; ++rep){
            int idx = tid + rep * 512;
            int d = idx >> 7, rr = idx & 127;
            float s = part8[rr][d][0] + part8[rr][d][1] + part8[rr][d][2] + part8[rr][d][3];
            t0f[d][rr] = s0p[rr] * s;
        }
        __syncthreads();

        // S8: q partials (W1 @ t0[d])
        {
            float acc8[DD];
            #pragma unroll
            for (int d = 0; d < DD; ++d) acc8[d] = 0.f;
            #pragma unroll
            for (int d = 0; d < DD; ++d){
                const float4* tv = (const float4*)(&t0f[d][0]);
                #pragma unroll
                for (int k4 = 0; k4 < 8; ++k4){
                    float4 tx = tv[q * 8 + k4];
                    acc8[d] += w1r[4*k4+0]*tx.x + w1r[4*k4+1]*tx.y + w1r[4*k4+2]*tx.z + w1r[4*k4+3]*tx.w;
                }
            }
            #pragma unroll
            for (int d = 0; d < DD; ++d) part8[r][d][q] = acc8[d];
        }
        __syncthreads();
        #pragma unroll
        for (int rep = 0; rep < 2; ++rep){
            int idx = tid + rep * 512;
            int d = idx >> 7, rr = idx & 127;
            float s = part8[rr][d][0] + part8[rr][d][1] + part8[rr][d][2] + part8[rr][d][3];
            qf[d][rr] = s1pL[rr] * s;
        }
        __syncthreads();

        // S9: R = tanh' * (Wv2row . q[d]) per row tid
        {
            const float4* qv = (const float4*)(&qf[0][0]) + dj * 32;
            float acc = 0.f;
            #pragma unroll
            for (int k4 = 0; k4 < 32; ++k4){
                float4 qx = qv[k4];
                acc += w2row[4*k4+0]*qx.x + w2row[4*k4+1]*qx.y + w2row[4*k4+2]*qx.z + w2row[4*k4+3]*qx.w;
            }
            Rv[tid] = tpj * acc;
        }
        __syncthreads();

        // h update: hn = h + a@V + y
        if (tid < SS){
            float y = 0.f, av = 0.f;
            #pragma unroll
            for (int d = 0; d < DD; ++d){
                y  += Rv[d * SS + tid];
                av += aL[d] * Vl[d * SS + tid];
            }
            hf[tid] = hf[tid] + av + y;
        }
        __syncthreads();

        // readout
        if (tid < OUTD){
            float acc = brL[tid];
            #pragma unroll
            for (int c = 0; c < SS; ++c) acc += WrL[tid * SS + c] * hf[c];
            out[(size_t)b * (NWIN + 1) * OUTD + (size_t)(n + 1) * OUTD + tid] = acc;
        }
    }
}

extern "C" void kernel_launch(void* const* d_in, const int* in_sizes, int n_in,
                              void* d_out, int out_size, void* d_ws, size_t ws_size,
                              hipStream_t stream){
    const float* x   = (const float*)d_in[1];
    const float* Wi0 = (const float*)d_in[2];
    const float* bi0 = (const float*)d_in[3];
    const float* Wi1 = (const float*)d_in[4];
    const float* bi1 = (const float*)d_in[5];
    const float* Wi2 = (const float*)d_in[6];
    const float* bi2 = (const float*)d_in[7];
    const float* Wv0 = (const float*)d_in[8];
    const float* bv0 = (const float*)d_in[9];
    const float* Wv1 = (const float*)d_in[10];
    const float* bv1 = (const float*)d_in[11];
    const float* Wv2 = (const float*)d_in[12];
    const float* bv2 = (const float*)d_in[13];
    const float* Wr  = (const float*)d_in[14];
    const float* br  = (const float*)d_in[15];
    float* out = (float*)d_out;

    float* s1w = (float*)d_ws;
    float* s2w = s1w + (size_t)BB * NWIN * DD;

    sig_kernel<<<(BB * NWIN + 255) / 256, 256, 0, stream>>>(x, s1w, s2w);
    scan_kernel<<<BB, 512, 0, stream>>>(x, Wi0, bi0, Wi1, bi1, Wi2, bi2,
                                        Wv0, bv0, Wv1, bv1, Wv2, bv2,
                                        Wr, br, s1w, s2w, out);
}